// Round 9
// baseline (604.717 us; speedup 1.0000x reference)
//
#include <hip/hip_runtime.h>
#include <hip/hip_bf16.h>
#include <cstdint>
#include <cstddef>

#define NNODES 50000
#define NEDGES 800000
#define D_IN   128
#define D_H    256
#define D_OUT  64
#define SCAN_BS 256
#define SCAN_NB ((NNODES + SCAN_BS - 1) / SCAN_BS)   // 196
#define BSH    9
#define BKN    (1 << BSH)                             // 512 nodes per bucket
#define NBKT   ((NNODES + BKN - 1) / BKN)             // 98
#define MAXB   12288                                  // cap per bucket (45 sigma)
#define CHUNK  2048

typedef __attribute__((ext_vector_type(8))) short bf16x8;
typedef __attribute__((ext_vector_type(4))) float f32x4;

__device__ __forceinline__ unsigned short f2bf(float f) {
    unsigned u = __builtin_bit_cast(unsigned, f);
    unsigned r = (u + 0x7FFFu + ((u >> 16) & 1u)) >> 16;
    return (unsigned short)r;
}
__device__ __forceinline__ float bf2f(unsigned short h) {
    unsigned u = ((unsigned)h) << 16;
    return __builtin_bit_cast(float, u);
}

// ---------------- CSR build: bin -> bucket hist -> scan -> single-owner scatter ----------------
// Edge packs to u32: (dst<<16)|src  (both < 65536)

__global__ __launch_bounds__(256) void k_bin(const int* __restrict__ adjA, const int* __restrict__ adjB,
                                             int* __restrict__ bcnt, unsigned* __restrict__ binned, int e) {
    __shared__ int h[NBKT], pfx[NBKT], put[NBKT], gbase[NBKT];
    __shared__ unsigned stage[CHUNK];
    const int g = blockIdx.y;
    const int* srcp = g ? adjB : adjA;
    const int* dstp = srcp + e;
    unsigned* outp = binned + (size_t)g * NBKT * MAXB;
    int* bc = bcnt + g * NBKT;
    const int tid = threadIdx.x;
    const int base = blockIdx.x * CHUNK;
    const int nrem = min(CHUNK, e - base);
    if (nrem <= 0) return;

    for (int t = tid; t < NBKT; t += 256) { h[t] = 0; put[t] = 0; }
    __syncthreads();

    unsigned pv[8];
    int bv[8];
    #pragma unroll
    for (int q = 0; q < 8; ++q) {
        int i = base + q * 256 + tid;
        bv[q] = -1;
        if (i < e) {
            int s = srcp[i];
            int d = dstp[i];
            pv[q] = ((unsigned)d << 16) | (unsigned)s;
            bv[q] = d >> BSH;
            atomicAdd(&h[bv[q]], 1);
        }
    }
    __syncthreads();
    if (tid == 0) {
        int r = 0;
        for (int k = 0; k < NBKT; ++k) { pfx[k] = r; r += h[k]; }
    }
    __syncthreads();
    #pragma unroll
    for (int q = 0; q < 8; ++q) {
        if (bv[q] >= 0) {
            int p = pfx[bv[q]] + atomicAdd(&put[bv[q]], 1);
            stage[p] = pv[q];
        }
    }
    __syncthreads();
    if (tid < NBKT && h[tid] > 0) gbase[tid] = atomicAdd(&bc[tid], h[tid]);
    __syncthreads();
    for (int idx = tid; idx < nrem; idx += 256) {
        unsigned v = stage[idx];
        int bb = v >> (16 + BSH);
        outp[(size_t)bb * MAXB + gbase[bb] + (idx - pfx[bb])] = v;
    }
}

// per-bucket LDS histogram -> coalesced cnt write (no global atomics)
__global__ __launch_bounds__(256) void k_hist_b(const unsigned* __restrict__ binned, const int* __restrict__ bcnt,
                                                int* __restrict__ cnt1, int* __restrict__ cnt2, int n) {
    __shared__ int lc[BKN];
    const int g = blockIdx.y;
    const int b = blockIdx.x;
    const unsigned* in = binned + (size_t)g * NBKT * MAXB + (size_t)b * MAXB;
    int* cnt = g ? cnt2 : cnt1;
    const int nb = bcnt[g * NBKT + b];
    const int base = b << BSH;
    for (int t = threadIdx.x; t < BKN; t += 256) lc[t] = 0;
    __syncthreads();
    for (int t = threadIdx.x; t < nb; t += 256) {
        unsigned v = in[t];
        atomicAdd(&lc[(v >> 16) & (BKN - 1)], 1);
    }
    __syncthreads();
    for (int t = threadIdx.x; t < BKN; t += 256)
        if (base + t < n) cnt[base + t] = lc[t];
}

__global__ __launch_bounds__(256) void k_scan_local2(const int* __restrict__ cnt1, const int* __restrict__ cnt2,
                                                     int* __restrict__ rp1, int* __restrict__ rp2,
                                                     int* __restrict__ bsum, int n) {
    __shared__ int s[SCAN_BS];
    const int g = blockIdx.x / SCAN_NB;
    const int blk = blockIdx.x - g * SCAN_NB;
    const int* cnt = g ? cnt2 : cnt1;
    int* rp = g ? rp2 : rp1;
    int t = threadIdx.x;
    int i = blk * SCAN_BS + t;
    int v = (i < n) ? cnt[i] : 0;
    int sum = v;
    s[t] = v;
    __syncthreads();
    #pragma unroll
    for (int off = 1; off < SCAN_BS; off <<= 1) {
        int u = (t >= off) ? s[t - off] : 0;
        __syncthreads();
        sum += u;
        s[t] = sum;
        __syncthreads();
    }
    if (i < n) rp[i] = sum - v;
    if (t == SCAN_BS - 1) bsum[blockIdx.x] = sum;
}

__global__ __launch_bounds__(256) void k_scan_top2(int* __restrict__ bsum) {
    __shared__ int s[SCAN_BS];
    int* b = bsum + blockIdx.x * SCAN_NB;
    int t = threadIdx.x;
    int v = (t < SCAN_NB) ? b[t] : 0;
    int sum = v;
    s[t] = v;
    __syncthreads();
    #pragma unroll
    for (int off = 1; off < SCAN_BS; off <<= 1) {
        int u = (t >= off) ? s[t - off] : 0;
        __syncthreads();
        sum += u;
        s[t] = sum;
        __syncthreads();
    }
    if (t < SCAN_NB) b[t] = sum - v;
}

__global__ __launch_bounds__(256) void k_scan_add2(int* __restrict__ rp1, int* __restrict__ rp2,
                                                   const int* __restrict__ bsum, int n) {
    const int g = blockIdx.x / SCAN_NB;
    const int blk = blockIdx.x - g * SCAN_NB;
    int* rp = g ? rp2 : rp1;
    int i = blk * SCAN_BS + threadIdx.x;
    if (i < n) rp[i] += bsum[blockIdx.x];
    if (i == 0) rp[n] = NEDGES;
}

__global__ void k_dinv2x(const int* __restrict__ cnt1, const int* __restrict__ cnt2,
                         float* __restrict__ dinv1, float* __restrict__ dinv2, int n) {
    int i = blockIdx.x * blockDim.x + threadIdx.x;
    if (i < n) dinv1[i] = rsqrtf((float)(cnt1[i] + 1));
    else if (i < 2 * n) dinv2[i - n] = rsqrtf((float)(cnt2[i - n] + 1));
}

// single-owner bucket scatter: sort into LDS, flush col coalesced (no global atomics)
__global__ __launch_bounds__(256) void k_scatter_lds(const unsigned* __restrict__ binned, const int* __restrict__ bcnt,
                                                     const int* __restrict__ rp1, const int* __restrict__ rp2,
                                                     int* __restrict__ col1, int* __restrict__ col2, int n) {
    __shared__ int lcur[BKN];
    __shared__ int srt[MAXB];
    const int g = blockIdx.y;
    const int b = blockIdx.x;
    const unsigned* in = binned + (size_t)g * NBKT * MAXB + (size_t)b * MAXB;
    const int* rp = g ? rp2 : rp1;
    int* col = g ? col2 : col1;
    const int base = b << BSH;
    const int rpb = rp[base];
    const int nb = bcnt[g * NBKT + b];
    for (int t = threadIdx.x; t < BKN; t += 256) {
        int node = base + t;
        lcur[t] = (node < n) ? rp[node] - rpb : 0;
    }
    __syncthreads();
    for (int t = threadIdx.x; t < nb; t += 256) {
        unsigned v = in[t];
        int pos = atomicAdd(&lcur[(v >> 16) & (BKN - 1)], 1);
        srt[pos] = (int)(v & 0xFFFFu);
    }
    __syncthreads();
    for (int t = threadIdx.x; t < nb; t += 256) col[rpb + t] = srt[t];
}

// ---------------- quantize: fp32 rows -> int16 rows + per-row scale ----------------

template<int F, bool PRESCALE>
__global__ __launch_bounds__(256) void k_quant(const float* __restrict__ in, const float* __restrict__ dscale,
                                               short* __restrict__ q, float* __restrict__ qs, int n) {
    constexpr int VPT = F / 64;
    const int lane = threadIdx.x & 63;
    const int i = blockIdx.x * 4 + (threadIdx.x >> 6);
    if (i >= n) return;
    float v[VPT];
    const float* p = in + (size_t)i * F + lane * VPT;
    if constexpr (VPT == 4) { float4 t = *(const float4*)p; v[0] = t.x; v[1] = t.y; v[2] = t.z; v[3] = t.w; }
    else if constexpr (VPT == 2) { float2 t = *(const float2*)p; v[0] = t.x; v[1] = t.y; }
    else v[0] = *p;
    if constexpr (PRESCALE) {
        float d = dscale[i];
        #pragma unroll
        for (int c = 0; c < VPT; ++c) v[c] *= d;
    }
    float m = 0.f;
    #pragma unroll
    for (int c = 0; c < VPT; ++c) m = fmaxf(m, fabsf(v[c]));
    #pragma unroll
    for (int off = 32; off > 0; off >>= 1) m = fmaxf(m, __shfl_xor(m, off));
    float inv = (m > 0.f) ? 32767.0f / m : 0.f;
    short* qp = q + (size_t)i * F + lane * VPT;
    if constexpr (VPT == 4) {
        short4 o;
        o.x = (short)__float2int_rn(v[0] * inv);
        o.y = (short)__float2int_rn(v[1] * inv);
        o.z = (short)__float2int_rn(v[2] * inv);
        o.w = (short)__float2int_rn(v[3] * inv);
        *(short4*)qp = o;
    } else if constexpr (VPT == 2) {
        short2 o;
        o.x = (short)__float2int_rn(v[0] * inv);
        o.y = (short)__float2int_rn(v[1] * inv);
        *(short2*)qp = o;
    } else {
        *qp = (short)__float2int_rn(v[0] * inv);
    }
    if (lane == 0) qs[i] = m * (1.0f / 32767.0f);
}

// ---------------- XCD-sliced aggregation over int16-quantized prescaled input ----------------
// Feature dim split into 64B slices (32 int16); slice pinned to XCD via blockIdx%8
// (round-robin dispatch) so each XCD's L2 holds only its 3.2 MB slice.
// Per wave: 1 dst node; 4 lane-groups of 16 process 4 edges concurrently (MLP x4),
// then 2-step shfl_xor cross-group reduce. Virtual edge idx beg-1 = self loop.

template<int F, int OUTM>
__global__ __launch_bounds__(256) void k_agg4(const short* __restrict__ q, const float* __restrict__ qs,
                                              const int* __restrict__ rp, const int* __restrict__ col,
                                              const float* __restrict__ dinv, const float* __restrict__ bias,
                                              void* __restrict__ outv, int n) {
    constexpr int NSL = F / 32;          // 32-col slices per row (8/4/2)
    constexpr int REP = 8 / NSL;         // node-chunk partitions per slice (1/2/4)
    const int blk = blockIdx.x;
    const int v8 = blk & 7;              // XCD id under round-robin dispatch
    const int sl = v8 % NSL;             // column slice
    const int r  = v8 / NSL;             // chunk partition
    const int chunk = (blk >> 3) * REP + r;
    const int wv = threadIdx.x >> 6;
    const int lane = threadIdx.x & 63;
    const int grp = lane >> 4;
    const int gl = lane & 15;
    const int i = chunk * 4 + wv;
    if (i >= n) return;
    const int c0 = sl * 32 + gl * 2;
    const short* qc = q + c0;

    float a0 = 0.f, a1 = 0.f;
    const int beg = rp[i], end = rp[i + 1];
    for (int idx = beg - 1 + grp; idx < end; idx += 4) {
        int j = (idx < beg) ? i : col[idx];
        float s = qs[j];
        short2 v = *(const short2*)(qc + (size_t)j * F);
        a0 += s * (float)v.x;
        a1 += s * (float)v.y;
    }
    a0 += __shfl_xor(a0, 16); a1 += __shfl_xor(a1, 16);
    a0 += __shfl_xor(a0, 32); a1 += __shfl_xor(a1, 32);
    if (grp != 0) return;

    const float di = dinv[i];
    const float v0 = a0 * di, v1 = a1 * di;
    if constexpr (OUTM == 0) {
        unsigned short* o = (unsigned short*)outv + (size_t)i * 2 * F + c0;
        unsigned short h0 = f2bf(v0), h1 = f2bf(v1);
        ushort2 hh; hh.x = h0; hh.y = h1;
        ushort2 ll; ll.x = f2bf(v0 - bf2f(h0)); ll.y = f2bf(v1 - bf2f(h1));
        *(ushort2*)o = hh;
        *(ushort2*)(o + F) = ll;
    } else {
        float* o = (float*)outv + (size_t)i * F + c0;
        float2 ov; ov.x = v0 + bias[c0]; ov.y = v1 + bias[c0 + 1];
        *(float2*)o = ov;
    }
}

// ---------------- fused weight preconvert ----------------

__device__ __forceinline__ void wconv1(const float* __restrict__ W, unsigned short* __restrict__ Th,
                                       unsigned short* __restrict__ Tl, int idx, int K, int Nc) {
    int k = idx / Nc, n = idx - k * Nc;
    float v = W[idx];
    unsigned short h = f2bf(v);
    unsigned short l = f2bf(v - bf2f(h));
    Th[(size_t)n * K + k] = h;
    Tl[(size_t)n * K + k] = l;
}

__global__ void k_wconv_all(const float* W1, const float* W2, const float* L1w, const float* L2w, const float* W3,
                            unsigned short* W1h, unsigned short* W1l, unsigned short* W2h, unsigned short* W2l,
                            unsigned short* L1h, unsigned short* L1l, unsigned short* L2h, unsigned short* L2l,
                            unsigned short* W3h, unsigned short* W3l) {
    int idx = blockIdx.x * blockDim.x + threadIdx.x;
    if (idx < 32768)        wconv1(W1, W1h, W1l, idx, D_IN, D_H);
    else if (idx < 98304)   wconv1(W2, W2h, W2l, idx - 32768, D_H, D_H);
    else if (idx < 131072)  wconv1(L1w, L1h, L1l, idx - 98304, D_H, D_IN);
    else if (idx < 163840)  wconv1(L2w, L2h, L2l, idx - 131072, D_IN, D_H);
    else if (idx < 180224)  wconv1(W3, W3h, W3l, idx - 163840, D_H, D_OUT);
}

// ---------------- MFMA GEMM (PAD=66 conflict-free, 128x64 tile, XCD swizzle) ----------------

template<bool RELU, bool BIAS, int OUTM>
__global__ __launch_bounds__(256) void k_gemm3(const unsigned short* __restrict__ Ahl,
        const unsigned short* __restrict__ Bth, const unsigned short* __restrict__ Btl,
        const float* __restrict__ bias, const float* __restrict__ dscale,
        void* __restrict__ Cv, int M, int K, int Nc, int ncb) {
    constexpr int PAD = 66;   // 132B stride (33 dwords, odd): conflict-free column reads
    __shared__ unsigned short As_h[128][PAD];
    __shared__ unsigned short As_l[128][PAD];
    __shared__ unsigned short Bs_h[64][PAD];
    __shared__ unsigned short Bs_l[64][PAD];

    // bijective XCD swizzle (m204): consecutive swz ids (same row-tile) share b%8
    const int nwg = gridDim.x;
    const int b = blockIdx.x;
    const int q8 = nwg >> 3, r8 = nwg & 7;
    const int xcd = b & 7;
    const int swz = (xcd < r8 ? xcd * (q8 + 1) : r8 * (q8 + 1) + (xcd - r8) * q8) + (b >> 3);
    const int row0 = (swz / ncb) * 128;
    const int col0 = (swz % ncb) * 64;

    const int tid = threadIdx.x;
    const int lane = tid & 63;
    const int wv = tid >> 6;

    f32x4 acc[2][4];
    #pragma unroll
    for (int m = 0; m < 2; ++m)
        #pragma unroll
        for (int n = 0; n < 4; ++n) acc[m][n] = (f32x4)(0.f);

    const int srow = tid >> 1;
    const int skh = (tid & 1) * 32;
    int arow = row0 + srow;
    if (arow >= M) arow = M - 1;
    const unsigned short* aph = Ahl + (size_t)arow * 2 * K + skh;
    const unsigned short* apl = aph + K;

    const int bn = tid >> 2;
    const int bko = (tid & 3) * 16;
    const unsigned short* bph = Bth + (size_t)(col0 + bn) * K + bko;
    const unsigned short* bpl = Btl + (size_t)(col0 + bn) * K + bko;

    const int fr = lane & 15;
    const int fk = (lane >> 4) * 8;

    const int nk = K >> 6;
    for (int kt = 0; kt < nk; ++kt) {
        uint4 ah0 = *(const uint4*)(aph + kt * 64);
        uint4 ah1 = *(const uint4*)(aph + kt * 64 + 8);
        uint4 ah2 = *(const uint4*)(aph + kt * 64 + 16);
        uint4 ah3 = *(const uint4*)(aph + kt * 64 + 24);
        uint4 al0 = *(const uint4*)(apl + kt * 64);
        uint4 al1 = *(const uint4*)(apl + kt * 64 + 8);
        uint4 al2 = *(const uint4*)(apl + kt * 64 + 16);
        uint4 al3 = *(const uint4*)(apl + kt * 64 + 24);
        uint4 bh0 = *(const uint4*)(bph + kt * 64);
        uint4 bh1 = *(const uint4*)(bph + kt * 64 + 8);
        uint4 bl0 = *(const uint4*)(bpl + kt * 64);
        uint4 bl1 = *(const uint4*)(bpl + kt * 64 + 8);

        __syncthreads();

        *(uint4*)&As_h[srow][skh] = ah0;
        *(uint4*)&As_h[srow][skh + 8] = ah1;
        *(uint4*)&As_h[srow][skh + 16] = ah2;
        *(uint4*)&As_h[srow][skh + 24] = ah3;
        *(uint4*)&As_l[srow][skh] = al0;
        *(uint4*)&As_l[srow][skh + 8] = al1;
        *(uint4*)&As_l[srow][skh + 16] = al2;
        *(uint4*)&As_l[srow][skh + 24] = al3;
        *(uint4*)&Bs_h[bn][bko] = bh0;
        *(uint4*)&Bs_h[bn][bko + 8] = bh1;
        *(uint4*)&Bs_l[bn][bko] = bl0;
        *(uint4*)&Bs_l[bn][bko + 8] = bl1;

        __syncthreads();

        #pragma unroll
        for (int ks = 0; ks < 2; ++ks) {
            const int ko = ks * 32 + fk;
            bf16x8 ah[2], al[2], bh[4], bl[4];
            #pragma unroll
            for (int m = 0; m < 2; ++m) {
                ah[m] = *(const bf16x8*)&As_h[wv * 32 + m * 16 + fr][ko];
                al[m] = *(const bf16x8*)&As_l[wv * 32 + m * 16 + fr][ko];
            }
            #pragma unroll
            for (int n = 0; n < 4; ++n) {
                bh[n] = *(const bf16x8*)&Bs_h[n * 16 + fr][ko];
                bl[n] = *(const bf16x8*)&Bs_l[n * 16 + fr][ko];
            }
            #pragma unroll
            for (int m = 0; m < 2; ++m)
                #pragma unroll
                for (int n = 0; n < 4; ++n) {
                    acc[m][n] = __builtin_amdgcn_mfma_f32_16x16x32_bf16(ah[m], bh[n], acc[m][n], 0, 0, 0);
                    acc[m][n] = __builtin_amdgcn_mfma_f32_16x16x32_bf16(ah[m], bl[n], acc[m][n], 0, 0, 0);
                    acc[m][n] = __builtin_amdgcn_mfma_f32_16x16x32_bf16(al[m], bh[n], acc[m][n], 0, 0, 0);
                }
        }
    }

    float bv[4];
    #pragma unroll
    for (int n = 0; n < 4; ++n) bv[n] = BIAS ? bias[col0 + n * 16 + fr] : 0.f;
    const int rbase = row0 + wv * 32 + (lane >> 4) * 4;
    #pragma unroll
    for (int m = 0; m < 2; ++m) {
        #pragma unroll
        for (int j = 0; j < 4; ++j) {
            const int r = rbase + m * 16 + j;
            if (r >= M) continue;
            float ds = 1.f;
            if constexpr (OUTM == 1) ds = dscale[r];
            #pragma unroll
            for (int n = 0; n < 4; ++n) {
                const int c = col0 + n * 16 + fr;
                float o = acc[m][n][j] + bv[n];
                if constexpr (RELU) o = fmaxf(o, 0.f);
                if constexpr (OUTM == 1) {
                    ((float*)Cv)[(size_t)r * Nc + c] = o * ds;
                } else {
                    unsigned short h = f2bf(o);
                    unsigned short l = f2bf(o - bf2f(h));
                    unsigned short* C2 = (unsigned short*)Cv + (size_t)r * 2 * Nc + c;
                    C2[0] = h;
                    C2[Nc] = l;
                }
            }
        }
    }
}

// ---------------- conditional softmax over 64 classes ----------------

__global__ __launch_bounds__(256) void k_softmax(float* __restrict__ out, const int* __restrict__ mode, int n) {
    if (*mode == 1) return;
    int lane = threadIdx.x & 63;
    int i = blockIdx.x * 4 + (threadIdx.x >> 6);
    if (i >= n) return;
    float v = out[(size_t)i * 64 + lane];
    float m = v;
    #pragma unroll
    for (int off = 32; off > 0; off >>= 1) m = fmaxf(m, __shfl_xor(m, off));
    float e = __expf(v - m);
    float s = e;
    #pragma unroll
    for (int off = 32; off > 0; off >>= 1) s += __shfl_xor(s, off);
    out[(size_t)i * 64 + lane] = e / s;
}

// ---------------- launch ----------------

extern "C" void kernel_launch(void* const* d_in, const int* in_sizes, int n_in,
                              void* d_out, int out_size, void* d_ws, size_t ws_size,
                              hipStream_t stream) {
    const float* x   = (const float*)d_in[0];
    const float* W1  = (const float*)d_in[1];
    const float* b1  = (const float*)d_in[2];
    const float* W2  = (const float*)d_in[3];
    const float* b2  = (const float*)d_in[4];
    const float* L1w = (const float*)d_in[5];
    const float* L1b = (const float*)d_in[6];
    const float* L2w = (const float*)d_in[7];
    const float* L2b = (const float*)d_in[8];
    const float* W3  = (const float*)d_in[9];
    const float* b3  = (const float*)d_in[10];
    const int* adj   = (const int*)d_in[11];
    const int* adj2  = (const int*)d_in[12];
    const int* mode  = (const int*)d_in[13];
    float* out = (float*)d_out;

    char* ws = (char*)d_ws;
    auto alloc = [&](size_t bytes) {
        char* p = ws;
        ws += (bytes + 255) & ~(size_t)255;
        return p;
    };
    char*  bufA  = alloc((size_t)NNODES * 256 * 4);   // 51.2 MB
    char*  bufB  = alloc((size_t)NNODES * 256 * 4);   // 51.2 MB
    int*   rp1   = (int*)alloc((NNODES + 1) * 4);
    int*   col1  = (int*)alloc((size_t)NEDGES * 4);
    int*   rp2   = (int*)alloc((NNODES + 1) * 4);
    int*   col2  = (int*)alloc((size_t)NEDGES * 4);
    float* dinv1 = (float*)alloc(NNODES * 4);
    float* dinv2 = (float*)alloc(NNODES * 4);
    int*   cnt1  = (int*)alloc((size_t)NNODES * 4);
    int*   cnt2  = (int*)alloc((size_t)NNODES * 4);
    int*   bsum  = (int*)alloc(2 * SCAN_NB * 4);
    int*   bcnt  = (int*)alloc(2 * NBKT * 4);
    float* qs    = (float*)alloc(NNODES * 4);
    unsigned short* W1h = (unsigned short*)alloc(D_IN * D_H * 2);
    unsigned short* W1l = (unsigned short*)alloc(D_IN * D_H * 2);
    unsigned short* W2h = (unsigned short*)alloc(D_H * D_H * 2);
    unsigned short* W2l = (unsigned short*)alloc(D_H * D_H * 2);
    unsigned short* L1h = (unsigned short*)alloc(D_H * D_IN * 2);
    unsigned short* L1l = (unsigned short*)alloc(D_H * D_IN * 2);
    unsigned short* L2h = (unsigned short*)alloc(D_IN * D_H * 2);
    unsigned short* L2l = (unsigned short*)alloc(D_IN * D_H * 2);
    unsigned short* W3h = (unsigned short*)alloc(D_H * D_OUT * 2);
    unsigned short* W3l = (unsigned short*)alloc(D_H * D_OUT * 2);
    // binned edge arrays alias bufA (consumed before bufA's first use); 2 * 98 * 12288 * 4B = 9.6 MB
    unsigned* binned = (unsigned*)bufA;

    const int AGB = (NNODES + 3) / 4;                 // 12500 (quant / softmax)
    const int MT = (NNODES + 127) / 128;
    const int BINB = (NEDGES + CHUNK - 1) / CHUNK;    // 391
    // sliced-agg grids: chunks=12500; REP=8/NSL chunk-partitions per 8-block group
    const int AG256 = 12500 * 8;                      // F=256: REP=1
    const int AG128 = ((12500 + 1) / 2) * 8;          // F=128: REP=2
    const int AG64  = ((12500 + 3) / 4) * 8;          // F=64:  REP=4

    // weights -> bf16 hi/lo transposed (one kernel)
    k_wconv_all<<<(180224 + 255) / 256, 256, 0, stream>>>(W1, W2, L1w, L2w, W3,
        W1h, W1l, W2h, W2l, L1h, L1l, L2h, L2l, W3h, W3l);

    // CSR build: bin (coalesced) -> bucket hist (LDS) -> scan -> dinv -> single-owner scatter
    hipMemsetAsync(bcnt, 0, 2 * NBKT * 4, stream);
    k_bin<<<dim3(BINB, 2), 256, 0, stream>>>(adj, adj2, bcnt, binned, NEDGES);
    k_hist_b<<<dim3(NBKT, 2), 256, 0, stream>>>(binned, bcnt, cnt1, cnt2, NNODES);
    k_scan_local2<<<2 * SCAN_NB, 256, 0, stream>>>(cnt1, cnt2, rp1, rp2, bsum, NNODES);
    k_scan_top2<<<2, 256, 0, stream>>>(bsum);
    k_scan_add2<<<2 * SCAN_NB, 256, 0, stream>>>(rp1, rp2, bsum, NNODES);
    k_dinv2x<<<(2 * NNODES + 255) / 256, 256, 0, stream>>>(cnt1, cnt2, dinv1, dinv2, NNODES);
    k_scatter_lds<<<dim3(NBKT, 2), 256, 0, stream>>>(binned, bcnt, rp1, rp2, col1, col2, NNODES);

    // q(x .* dinv1) -> bufA (int16[50000][128]) + qs
    k_quant<128, true><<<AGB, 256, 0, stream>>>(x, dinv1, (short*)bufA, qs, NNODES);
    // conv1 agg (sliced): bufA(q128) -> bufB (hl,128)
    k_agg4<128, 0><<<AG128, 256, 0, stream>>>((const short*)bufA, qs, rp1, col1, dinv1, nullptr, bufB, NNODES);
    // conv1 gemm: relu((.)W1+b1) * dinv2 -> bufA (f32,256)
    k_gemm3<true, true, 1><<<MT * 4, 256, 0, stream>>>(
        (const unsigned short*)bufB, W1h, W1l, b1, dinv2, bufA, NNODES, D_IN, D_H, 4);
    // quantize: bufA(f32,256) -> bufB (q256) + qs
    k_quant<256, false><<<AGB, 256, 0, stream>>>((const float*)bufA, nullptr, (short*)bufB, qs, NNODES);
    // conv2 agg (sliced): bufB(q256) -> bufA (hl,256)
    k_agg4<256, 0><<<AG256, 256, 0, stream>>>((const short*)bufB, qs, rp2, col2, dinv2, nullptr, bufA, NNODES);
    // conv2 gemm: relu((.)W2+b2) -> bufB (hl,256)
    k_gemm3<true, true, 2><<<MT * 4, 256, 0, stream>>>(
        (const unsigned short*)bufA, W2h, W2l, b2, nullptr, bufB, NNODES, D_H, D_H, 4);
    // L1: relu((.)L1w+b) -> bufA (hl,128)
    k_gemm3<true, true, 2><<<MT * 2, 256, 0, stream>>>(
        (const unsigned short*)bufB, L1h, L1l, L1b, nullptr, bufA, NNODES, D_H, D_IN, 2);
    // L2: relu((.)L2w+b) -> bufB (hl,256)
    k_gemm3<true, true, 2><<<MT * 4, 256, 0, stream>>>(
        (const unsigned short*)bufA, L2h, L2l, L2b, nullptr, bufB, NNODES, D_IN, D_H, 4);
    // conv3 gemm: ((.)W3) * dinv2 -> bufA (f32,64)
    k_gemm3<false, false, 1><<<MT * 1, 256, 0, stream>>>(
        (const unsigned short*)bufB, W3h, W3l, nullptr, dinv2, bufA, NNODES, D_H, D_OUT, 1);
    // quantize: bufA(f32,64) -> bufB (q64) + qs
    k_quant<64, false><<<AGB, 256, 0, stream>>>((const float*)bufA, nullptr, (short*)bufB, qs, NNODES);
    // conv3 agg (sliced): bufB(q64) -> out (f32 + b3)
    k_agg4<64, 1><<<AG64, 256, 0, stream>>>((const short*)bufB, qs, rp2, col2, dinv2, b3, out, NNODES);
    // optional softmax (mode != 1)
    k_softmax<<<AGB, 256, 0, stream>>>(out, mode, NNODES);
}

// Round 10
// 351.863 us; speedup vs baseline: 1.7186x; 1.7186x over previous
//
#include <hip/hip_runtime.h>
#include <hip/hip_bf16.h>
#include <cstdint>
#include <cstddef>

#define NNODES 50000
#define NEDGES 800000
#define D_IN   128
#define D_H    256
#define D_OUT  64
#define BSH    9
#define BKN    (1 << BSH)                             // 512 nodes per bucket
#define NBKT   ((NNODES + BKN - 1) / BKN)             // 98
#define MAXB   12288                                  // cap per bucket (45 sigma)
#define CHUNK  2048

typedef __attribute__((ext_vector_type(8))) short bf16x8;
typedef __attribute__((ext_vector_type(4))) float f32x4;

__device__ __forceinline__ unsigned short f2bf(float f) {
    unsigned u = __builtin_bit_cast(unsigned, f);
    unsigned r = (u + 0x7FFFu + ((u >> 16) & 1u)) >> 16;
    return (unsigned short)r;
}
__device__ __forceinline__ float bf2f(unsigned short h) {
    unsigned u = ((unsigned)h) << 16;
    return __builtin_bit_cast(float, u);
}

// ---------------- CSR build: bin -> bucket scan -> fused per-bucket CSR ----------------
// Edge packs to u32: (dst<<16)|src  (both < 65536)

__global__ __launch_bounds__(256) void k_bin(const int* __restrict__ adjA, const int* __restrict__ adjB,
                                             int* __restrict__ bcnt, unsigned* __restrict__ binned, int e) {
    __shared__ int h[NBKT], pfx[NBKT], put[NBKT], gbase[NBKT];
    __shared__ unsigned stage[CHUNK];
    const int g = blockIdx.y;
    const int* srcp = g ? adjB : adjA;
    const int* dstp = srcp + e;
    unsigned* outp = binned + (size_t)g * NBKT * MAXB;
    int* bc = bcnt + g * NBKT;
    const int tid = threadIdx.x;
    const int base = blockIdx.x * CHUNK;
    const int nrem = min(CHUNK, e - base);
    if (nrem <= 0) return;

    for (int t = tid; t < NBKT; t += 256) { h[t] = 0; put[t] = 0; }
    __syncthreads();

    unsigned pv[8];
    int bv[8];
    #pragma unroll
    for (int q = 0; q < 8; ++q) {
        int i = base + q * 256 + tid;
        bv[q] = -1;
        if (i < e) {
            int s = srcp[i];
            int d = dstp[i];
            pv[q] = ((unsigned)d << 16) | (unsigned)s;
            bv[q] = d >> BSH;
            atomicAdd(&h[bv[q]], 1);
        }
    }
    __syncthreads();
    if (tid == 0) {
        int r = 0;
        for (int k = 0; k < NBKT; ++k) { pfx[k] = r; r += h[k]; }
    }
    __syncthreads();
    #pragma unroll
    for (int q = 0; q < 8; ++q) {
        if (bv[q] >= 0) {
            int p = pfx[bv[q]] + atomicAdd(&put[bv[q]], 1);
            stage[p] = pv[q];
        }
    }
    __syncthreads();
    if (tid < NBKT && h[tid] > 0) gbase[tid] = atomicAdd(&bc[tid], h[tid]);
    __syncthreads();
    for (int idx = tid; idx < nrem; idx += 256) {
        unsigned v = stage[idx];
        int bb = v >> (16 + BSH);
        outp[(size_t)bb * MAXB + gbase[bb] + (idx - pfx[bb])] = v;
    }
}

// exclusive scan of 98 bucket counts per graph -> bucket edge-bases; rp[n]=E
__global__ void k_bktscan(const int* __restrict__ bcnt, int* __restrict__ bbase,
                          int* __restrict__ rp1, int* __restrict__ rp2) {
    __shared__ int s[2][NBKT];
    int t = threadIdx.x;
    if (t < NBKT) s[0][t] = bcnt[t];
    else if (t < 2 * NBKT) s[1][t - NBKT] = bcnt[t];
    __syncthreads();
    if (t < 2) {
        int r = 0;
        for (int k = 0; k < NBKT; ++k) { int v = s[t][k]; s[t][k] = r; r += v; }
    }
    __syncthreads();
    if (t < NBKT) bbase[t] = s[0][t];
    else if (t < 2 * NBKT) bbase[t] = s[1][t - NBKT];
    if (t == 0) { rp1[NNODES] = NEDGES; rp2[NNODES] = NEDGES; }
}

// fused per-bucket: LDS hist -> LDS scan -> rp/dinv coalesced write -> LDS scatter -> col flush
__global__ __launch_bounds__(256) void k_csr_bucket(const unsigned* __restrict__ binned,
                                                    const int* __restrict__ bcnt, const int* __restrict__ bbase,
                                                    int* __restrict__ rp1, int* __restrict__ rp2,
                                                    float* __restrict__ dinv1, float* __restrict__ dinv2,
                                                    int* __restrict__ col1, int* __restrict__ col2, int n) {
    __shared__ int lc[BKN];      // per-node degree
    __shared__ int loff[BKN];    // per-node exclusive offset within bucket (then cursor)
    __shared__ int ps[256];
    __shared__ int srt[MAXB];
    const int g = blockIdx.y;
    const int b = blockIdx.x;
    const unsigned* in = binned + (size_t)g * NBKT * MAXB + (size_t)b * MAXB;
    int* rp = g ? rp2 : rp1;
    float* dinv = g ? dinv2 : dinv1;
    int* col = g ? col2 : col1;
    const int nb = bcnt[g * NBKT + b];
    const int base0 = bbase[g * NBKT + b];
    const int nodebase = b << BSH;
    const int tid = threadIdx.x;

    for (int t = tid; t < BKN; t += 256) lc[t] = 0;
    __syncthreads();
    for (int t = tid; t < nb; t += 256)
        atomicAdd(&lc[(in[t] >> 16) & (BKN - 1)], 1);
    __syncthreads();
    // exclusive scan over 512 counts: thread t handles elems 2t, 2t+1
    int c0 = lc[2 * tid], c1 = lc[2 * tid + 1];
    int pair = c0 + c1;
    int sum = pair;
    ps[tid] = pair;
    __syncthreads();
    #pragma unroll
    for (int off = 1; off < 256; off <<= 1) {
        int u = (tid >= off) ? ps[tid - off] : 0;
        __syncthreads();
        sum += u;
        ps[tid] = sum;
        __syncthreads();
    }
    int excl = sum - pair;
    loff[2 * tid] = excl;
    loff[2 * tid + 1] = excl + c0;
    __syncthreads();
    // rp + dinv coalesced
    for (int t = tid; t < BKN; t += 256) {
        int node = nodebase + t;
        if (node < n) {
            rp[node] = base0 + loff[t];
            dinv[node] = rsqrtf((float)(lc[t] + 1));
        }
    }
    __syncthreads();
    // scatter into LDS (loff reused as cursor)
    for (int t = tid; t < nb; t += 256) {
        unsigned v = in[t];
        int pos = atomicAdd(&loff[(v >> 16) & (BKN - 1)], 1);
        srt[pos] = (int)(v & 0xFFFFu);
    }
    __syncthreads();
    for (int t = tid; t < nb; t += 256) col[base0 + t] = srt[t];
}

// ---------------- quantize: fp32 rows -> int16 rows + per-row scale ----------------

template<int F, bool PRESCALE>
__global__ __launch_bounds__(256) void k_quant(const float* __restrict__ in, const float* __restrict__ dscale,
                                               short* __restrict__ q, float* __restrict__ qs, int n) {
    constexpr int VPT = F / 64;
    const int lane = threadIdx.x & 63;
    const int i = blockIdx.x * 4 + (threadIdx.x >> 6);
    if (i >= n) return;
    float v[VPT];
    const float* p = in + (size_t)i * F + lane * VPT;
    if constexpr (VPT == 4) { float4 t = *(const float4*)p; v[0] = t.x; v[1] = t.y; v[2] = t.z; v[3] = t.w; }
    else if constexpr (VPT == 2) { float2 t = *(const float2*)p; v[0] = t.x; v[1] = t.y; }
    else v[0] = *p;
    if constexpr (PRESCALE) {
        float d = dscale[i];
        #pragma unroll
        for (int c = 0; c < VPT; ++c) v[c] *= d;
    }
    float m = 0.f;
    #pragma unroll
    for (int c = 0; c < VPT; ++c) m = fmaxf(m, fabsf(v[c]));
    #pragma unroll
    for (int off = 32; off > 0; off >>= 1) m = fmaxf(m, __shfl_xor(m, off));
    float inv = (m > 0.f) ? 32767.0f / m : 0.f;
    short* qp = q + (size_t)i * F + lane * VPT;
    if constexpr (VPT == 4) {
        short4 o;
        o.x = (short)__float2int_rn(v[0] * inv);
        o.y = (short)__float2int_rn(v[1] * inv);
        o.z = (short)__float2int_rn(v[2] * inv);
        o.w = (short)__float2int_rn(v[3] * inv);
        *(short4*)qp = o;
    } else if constexpr (VPT == 2) {
        short2 o;
        o.x = (short)__float2int_rn(v[0] * inv);
        o.y = (short)__float2int_rn(v[1] * inv);
        *(short2*)qp = o;
    } else {
        *qp = (short)__float2int_rn(v[0] * inv);
    }
    if (lane == 0) qs[i] = m * (1.0f / 32767.0f);
}

// ---------------- Aggregation over int16-quantized prescaled input (round-8 proven) ----------------

template<int F, int OUTM>
__global__ __launch_bounds__(256) void k_agg3(const short* __restrict__ q, const float* __restrict__ qs,
                                              const int* __restrict__ rp, const int* __restrict__ col,
                                              const float* __restrict__ dinv, const float* __restrict__ bias,
                                              void* __restrict__ outv, int n) {
    constexpr int VPT = F / 64;
    const int lane = threadIdx.x & 63;
    const int i = blockIdx.x * 4 + (threadIdx.x >> 6);
    if (i >= n) return;
    const short* ql = q + lane * VPT;
    float acc[VPT];
    #pragma unroll
    for (int c = 0; c < VPT; ++c) acc[c] = 0.f;

    int k = rp[i], end = rp[i + 1];

    auto body1 = [&](int j) {
        float s = qs[j];
        const short* pj = ql + (size_t)j * F;
        if constexpr (VPT == 4) {
            short4 v = *(const short4*)pj;
            acc[0] += s * (float)v.x; acc[1] += s * (float)v.y;
            acc[2] += s * (float)v.z; acc[3] += s * (float)v.w;
        } else if constexpr (VPT == 2) {
            short2 v = *(const short2*)pj;
            acc[0] += s * (float)v.x; acc[1] += s * (float)v.y;
        } else {
            acc[0] += s * (float)(*pj);
        }
    };

    body1(i);  // self loop
    for (; k + 4 <= end; k += 4) {
        int j0 = col[k], j1 = col[k + 1], j2 = col[k + 2], j3 = col[k + 3];
        float s0 = qs[j0], s1 = qs[j1], s2 = qs[j2], s3 = qs[j3];
        if constexpr (VPT == 4) {
            short4 v0 = *(const short4*)(ql + (size_t)j0 * F);
            short4 v1 = *(const short4*)(ql + (size_t)j1 * F);
            short4 v2 = *(const short4*)(ql + (size_t)j2 * F);
            short4 v3 = *(const short4*)(ql + (size_t)j3 * F);
            acc[0] += s0 * (float)v0.x + s1 * (float)v1.x + s2 * (float)v2.x + s3 * (float)v3.x;
            acc[1] += s0 * (float)v0.y + s1 * (float)v1.y + s2 * (float)v2.y + s3 * (float)v3.y;
            acc[2] += s0 * (float)v0.z + s1 * (float)v1.z + s2 * (float)v2.z + s3 * (float)v3.z;
            acc[3] += s0 * (float)v0.w + s1 * (float)v1.w + s2 * (float)v2.w + s3 * (float)v3.w;
        } else if constexpr (VPT == 2) {
            short2 v0 = *(const short2*)(ql + (size_t)j0 * F);
            short2 v1 = *(const short2*)(ql + (size_t)j1 * F);
            short2 v2 = *(const short2*)(ql + (size_t)j2 * F);
            short2 v3 = *(const short2*)(ql + (size_t)j3 * F);
            acc[0] += s0 * (float)v0.x + s1 * (float)v1.x + s2 * (float)v2.x + s3 * (float)v3.x;
            acc[1] += s0 * (float)v0.y + s1 * (float)v1.y + s2 * (float)v2.y + s3 * (float)v3.y;
        } else {
            float v0 = (float)ql[(size_t)j0 * F];
            float v1 = (float)ql[(size_t)j1 * F];
            float v2 = (float)ql[(size_t)j2 * F];
            float v3 = (float)ql[(size_t)j3 * F];
            acc[0] += s0 * v0 + s1 * v1 + s2 * v2 + s3 * v3;
        }
    }
    for (; k < end; ++k) body1(col[k]);

    float di = dinv[i];
    if constexpr (OUTM == 0) {
        unsigned short* o = (unsigned short*)outv + (size_t)i * 2 * F + lane * VPT;
        #pragma unroll
        for (int c = 0; c < VPT; ++c) {
            float val = acc[c] * di;
            unsigned short h = f2bf(val);
            unsigned short l = f2bf(val - bf2f(h));
            o[c] = h;
            o[F + c] = l;
        }
    } else {
        float* o = (float*)outv + (size_t)i * F + lane * VPT;
        #pragma unroll
        for (int c = 0; c < VPT; ++c) o[c] = acc[c] * di + bias[lane * VPT + c];
    }
}

// ---------------- fused weight preconvert ----------------

__device__ __forceinline__ void wconv1(const float* __restrict__ W, unsigned short* __restrict__ Th,
                                       unsigned short* __restrict__ Tl, int idx, int K, int Nc) {
    int k = idx / Nc, n = idx - k * Nc;
    float v = W[idx];
    unsigned short h = f2bf(v);
    unsigned short l = f2bf(v - bf2f(h));
    Th[(size_t)n * K + k] = h;
    Tl[(size_t)n * K + k] = l;
}

__global__ void k_wconv_all(const float* W1, const float* W2, const float* L1w, const float* L2w, const float* W3,
                            unsigned short* W1h, unsigned short* W1l, unsigned short* W2h, unsigned short* W2l,
                            unsigned short* L1h, unsigned short* L1l, unsigned short* L2h, unsigned short* L2l,
                            unsigned short* W3h, unsigned short* W3l) {
    int idx = blockIdx.x * blockDim.x + threadIdx.x;
    if (idx < 32768)        wconv1(W1, W1h, W1l, idx, D_IN, D_H);
    else if (idx < 98304)   wconv1(W2, W2h, W2l, idx - 32768, D_H, D_H);
    else if (idx < 131072)  wconv1(L1w, L1h, L1l, idx - 98304, D_H, D_IN);
    else if (idx < 163840)  wconv1(L2w, L2h, L2l, idx - 131072, D_IN, D_H);
    else if (idx < 180224)  wconv1(W3, W3h, W3l, idx - 163840, D_H, D_OUT);
}

// ---------------- MFMA GEMM (PAD=66 conflict-free, 128x64 tile, XCD swizzle) ----------------

template<bool RELU, bool BIAS, int OUTM>
__global__ __launch_bounds__(256) void k_gemm3(const unsigned short* __restrict__ Ahl,
        const unsigned short* __restrict__ Bth, const unsigned short* __restrict__ Btl,
        const float* __restrict__ bias, const float* __restrict__ dscale,
        void* __restrict__ Cv, int M, int K, int Nc, int ncb) {
    constexpr int PAD = 66;   // 132B stride (33 dwords, odd): conflict-free column reads
    __shared__ unsigned short As_h[128][PAD];
    __shared__ unsigned short As_l[128][PAD];
    __shared__ unsigned short Bs_h[64][PAD];
    __shared__ unsigned short Bs_l[64][PAD];

    // bijective XCD swizzle (m204): consecutive swz ids (same row-tile) share b%8
    const int nwg = gridDim.x;
    const int b = blockIdx.x;
    const int q8 = nwg >> 3, r8 = nwg & 7;
    const int xcd = b & 7;
    const int swz = (xcd < r8 ? xcd * (q8 + 1) : r8 * (q8 + 1) + (xcd - r8) * q8) + (b >> 3);
    const int row0 = (swz / ncb) * 128;
    const int col0 = (swz % ncb) * 64;

    const int tid = threadIdx.x;
    const int lane = tid & 63;
    const int wv = tid >> 6;

    f32x4 acc[2][4];
    #pragma unroll
    for (int m = 0; m < 2; ++m)
        #pragma unroll
        for (int n = 0; n < 4; ++n) acc[m][n] = (f32x4)(0.f);

    const int srow = tid >> 1;
    const int skh = (tid & 1) * 32;
    int arow = row0 + srow;
    if (arow >= M) arow = M - 1;
    const unsigned short* aph = Ahl + (size_t)arow * 2 * K + skh;
    const unsigned short* apl = aph + K;

    const int bn = tid >> 2;
    const int bko = (tid & 3) * 16;
    const unsigned short* bph = Bth + (size_t)(col0 + bn) * K + bko;
    const unsigned short* bpl = Btl + (size_t)(col0 + bn) * K + bko;

    const int fr = lane & 15;
    const int fk = (lane >> 4) * 8;

    const int nk = K >> 6;
    for (int kt = 0; kt < nk; ++kt) {
        uint4 ah0 = *(const uint4*)(aph + kt * 64);
        uint4 ah1 = *(const uint4*)(aph + kt * 64 + 8);
        uint4 ah2 = *(const uint4*)(aph + kt * 64 + 16);
        uint4 ah3 = *(const uint4*)(aph + kt * 64 + 24);
        uint4 al0 = *(const uint4*)(apl + kt * 64);
        uint4 al1 = *(const uint4*)(apl + kt * 64 + 8);
        uint4 al2 = *(const uint4*)(apl + kt * 64 + 16);
        uint4 al3 = *(const uint4*)(apl + kt * 64 + 24);
        uint4 bh0 = *(const uint4*)(bph + kt * 64);
        uint4 bh1 = *(const uint4*)(bph + kt * 64 + 8);
        uint4 bl0 = *(const uint4*)(bpl + kt * 64);
        uint4 bl1 = *(const uint4*)(bpl + kt * 64 + 8);

        __syncthreads();

        *(uint4*)&As_h[srow][skh] = ah0;
        *(uint4*)&As_h[srow][skh + 8] = ah1;
        *(uint4*)&As_h[srow][skh + 16] = ah2;
        *(uint4*)&As_h[srow][skh + 24] = ah3;
        *(uint4*)&As_l[srow][skh] = al0;
        *(uint4*)&As_l[srow][skh + 8] = al1;
        *(uint4*)&As_l[srow][skh + 16] = al2;
        *(uint4*)&As_l[srow][skh + 24] = al3;
        *(uint4*)&Bs_h[bn][bko] = bh0;
        *(uint4*)&Bs_h[bn][bko + 8] = bh1;
        *(uint4*)&Bs_l[bn][bko] = bl0;
        *(uint4*)&Bs_l[bn][bko + 8] = bl1;

        __syncthreads();

        #pragma unroll
        for (int ks = 0; ks < 2; ++ks) {
            const int ko = ks * 32 + fk;
            bf16x8 ah[2], al[2], bh[4], bl[4];
            #pragma unroll
            for (int m = 0; m < 2; ++m) {
                ah[m] = *(const bf16x8*)&As_h[wv * 32 + m * 16 + fr][ko];
                al[m] = *(const bf16x8*)&As_l[wv * 32 + m * 16 + fr][ko];
            }
            #pragma unroll
            for (int n = 0; n < 4; ++n) {
                bh[n] = *(const bf16x8*)&Bs_h[n * 16 + fr][ko];
                bl[n] = *(const bf16x8*)&Bs_l[n * 16 + fr][ko];
            }
            #pragma unroll
            for (int m = 0; m < 2; ++m)
                #pragma unroll
                for (int n = 0; n < 4; ++n) {
                    acc[m][n] = __builtin_amdgcn_mfma_f32_16x16x32_bf16(ah[m], bh[n], acc[m][n], 0, 0, 0);
                    acc[m][n] = __builtin_amdgcn_mfma_f32_16x16x32_bf16(ah[m], bl[n], acc[m][n], 0, 0, 0);
                    acc[m][n] = __builtin_amdgcn_mfma_f32_16x16x32_bf16(al[m], bh[n], acc[m][n], 0, 0, 0);
                }
        }
    }

    float bv[4];
    #pragma unroll
    for (int n = 0; n < 4; ++n) bv[n] = BIAS ? bias[col0 + n * 16 + fr] : 0.f;
    const int rbase = row0 + wv * 32 + (lane >> 4) * 4;
    #pragma unroll
    for (int m = 0; m < 2; ++m) {
        #pragma unroll
        for (int j = 0; j < 4; ++j) {
            const int r = rbase + m * 16 + j;
            if (r >= M) continue;
            float ds = 1.f;
            if constexpr (OUTM == 1) ds = dscale[r];
            #pragma unroll
            for (int n = 0; n < 4; ++n) {
                const int c = col0 + n * 16 + fr;
                float o = acc[m][n][j] + bv[n];
                if constexpr (RELU) o = fmaxf(o, 0.f);
                if constexpr (OUTM == 1) {
                    ((float*)Cv)[(size_t)r * Nc + c] = o * ds;
                } else {
                    unsigned short h = f2bf(o);
                    unsigned short l = f2bf(o - bf2f(h));
                    unsigned short* C2 = (unsigned short*)Cv + (size_t)r * 2 * Nc + c;
                    C2[0] = h;
                    C2[Nc] = l;
                }
            }
        }
    }
}

// ---------------- conditional softmax over 64 classes ----------------

__global__ __launch_bounds__(256) void k_softmax(float* __restrict__ out, const int* __restrict__ mode, int n) {
    if (*mode == 1) return;
    int lane = threadIdx.x & 63;
    int i = blockIdx.x * 4 + (threadIdx.x >> 6);
    if (i >= n) return;
    float v = out[(size_t)i * 64 + lane];
    float m = v;
    #pragma unroll
    for (int off = 32; off > 0; off >>= 1) m = fmaxf(m, __shfl_xor(m, off));
    float e = __expf(v - m);
    float s = e;
    #pragma unroll
    for (int off = 32; off > 0; off >>= 1) s += __shfl_xor(s, off);
    out[(size_t)i * 64 + lane] = e / s;
}

// ---------------- launch ----------------

extern "C" void kernel_launch(void* const* d_in, const int* in_sizes, int n_in,
                              void* d_out, int out_size, void* d_ws, size_t ws_size,
                              hipStream_t stream) {
    const float* x   = (const float*)d_in[0];
    const float* W1  = (const float*)d_in[1];
    const float* b1  = (const float*)d_in[2];
    const float* W2  = (const float*)d_in[3];
    const float* b2  = (const float*)d_in[4];
    const float* L1w = (const float*)d_in[5];
    const float* L1b = (const float*)d_in[6];
    const float* L2w = (const float*)d_in[7];
    const float* L2b = (const float*)d_in[8];
    const float* W3  = (const float*)d_in[9];
    const float* b3  = (const float*)d_in[10];
    const int* adj   = (const int*)d_in[11];
    const int* adj2  = (const int*)d_in[12];
    const int* mode  = (const int*)d_in[13];
    float* out = (float*)d_out;

    char* ws = (char*)d_ws;
    auto alloc = [&](size_t bytes) {
        char* p = ws;
        ws += (bytes + 255) & ~(size_t)255;
        return p;
    };
    char*  bufA  = alloc((size_t)NNODES * 256 * 4);   // 51.2 MB
    char*  bufB  = alloc((size_t)NNODES * 256 * 4);   // 51.2 MB
    int*   rp1   = (int*)alloc((NNODES + 1) * 4);
    int*   col1  = (int*)alloc((size_t)NEDGES * 4);
    int*   rp2   = (int*)alloc((NNODES + 1) * 4);
    int*   col2  = (int*)alloc((size_t)NEDGES * 4);
    float* dinv1 = (float*)alloc(NNODES * 4);
    float* dinv2 = (float*)alloc(NNODES * 4);
    int*   bcnt  = (int*)alloc(2 * NBKT * 4);
    int*   bbase = (int*)alloc(2 * NBKT * 4);
    float* qs    = (float*)alloc(NNODES * 4);
    unsigned short* W1h = (unsigned short*)alloc(D_IN * D_H * 2);
    unsigned short* W1l = (unsigned short*)alloc(D_IN * D_H * 2);
    unsigned short* W2h = (unsigned short*)alloc(D_H * D_H * 2);
    unsigned short* W2l = (unsigned short*)alloc(D_H * D_H * 2);
    unsigned short* L1h = (unsigned short*)alloc(D_H * D_IN * 2);
    unsigned short* L1l = (unsigned short*)alloc(D_H * D_IN * 2);
    unsigned short* L2h = (unsigned short*)alloc(D_IN * D_H * 2);
    unsigned short* L2l = (unsigned short*)alloc(D_IN * D_H * 2);
    unsigned short* W3h = (unsigned short*)alloc(D_H * D_OUT * 2);
    unsigned short* W3l = (unsigned short*)alloc(D_H * D_OUT * 2);
    // binned edge arrays alias bufA (consumed before bufA's first use); 2 * 98 * 12288 * 4B = 9.6 MB
    unsigned* binned = (unsigned*)bufA;

    const int AGB = (NNODES + 3) / 4;
    const int MT = (NNODES + 127) / 128;
    const int BINB = (NEDGES + CHUNK - 1) / CHUNK;    // 391

    // weights -> bf16 hi/lo transposed (one kernel)
    k_wconv_all<<<(180224 + 255) / 256, 256, 0, stream>>>(W1, W2, L1w, L2w, W3,
        W1h, W1l, W2h, W2l, L1h, L1l, L2h, L2l, W3h, W3l);

    // CSR build: bin (coalesced) -> bucket scan (tiny) -> fused per-bucket CSR
    hipMemsetAsync(bcnt, 0, 2 * NBKT * 4, stream);
    k_bin<<<dim3(BINB, 2), 256, 0, stream>>>(adj, adj2, bcnt, binned, NEDGES);
    k_bktscan<<<1, 256, 0, stream>>>(bcnt, bbase, rp1, rp2);
    k_csr_bucket<<<dim3(NBKT, 2), 256, 0, stream>>>(binned, bcnt, bbase, rp1, rp2,
                                                    dinv1, dinv2, col1, col2, NNODES);

    // q(x .* dinv1) -> bufA (int16[50000][128]) + qs
    k_quant<128, true><<<AGB, 256, 0, stream>>>(x, dinv1, (short*)bufA, qs, NNODES);
    // conv1 agg: bufA(q128) -> bufB (hl,128)
    k_agg3<128, 0><<<AGB, 256, 0, stream>>>((const short*)bufA, qs, rp1, col1, dinv1, nullptr, bufB, NNODES);
    // conv1 gemm: relu((.)W1+b1) * dinv2 -> bufA (f32,256)
    k_gemm3<true, true, 1><<<MT * 4, 256, 0, stream>>>(
        (const unsigned short*)bufB, W1h, W1l, b1, dinv2, bufA, NNODES, D_IN, D_H, 4);
    // quantize: bufA(f32,256) -> bufB (q256) + qs
    k_quant<256, false><<<AGB, 256, 0, stream>>>((const float*)bufA, nullptr, (short*)bufB, qs, NNODES);
    // conv2 agg: bufB(q256) -> bufA (hl,256)
    k_agg3<256, 0><<<AGB, 256, 0, stream>>>((const short*)bufB, qs, rp2, col2, dinv2, nullptr, bufA, NNODES);
    // conv2 gemm: relu((.)W2+b2) -> bufB (hl,256)
    k_gemm3<true, true, 2><<<MT * 4, 256, 0, stream>>>(
        (const unsigned short*)bufA, W2h, W2l, b2, nullptr, bufB, NNODES, D_H, D_H, 4);
    // L1: relu((.)L1w+b) -> bufA (hl,128)
    k_gemm3<true, true, 2><<<MT * 2, 256, 0, stream>>>(
        (const unsigned short*)bufB, L1h, L1l, L1b, nullptr, bufA, NNODES, D_H, D_IN, 2);
    // L2: relu((.)L2w+b) -> bufB (hl,256)
    k_gemm3<true, true, 2><<<MT * 4, 256, 0, stream>>>(
        (const unsigned short*)bufA, L2h, L2l, L2b, nullptr, bufB, NNODES, D_IN, D_H, 4);
    // conv3 gemm: ((.)W3) * dinv2 -> bufA (f32,64)
    k_gemm3<false, false, 1><<<MT * 1, 256, 0, stream>>>(
        (const unsigned short*)bufB, W3h, W3l, nullptr, dinv2, bufA, NNODES, D_H, D_OUT, 1);
    // quantize: bufA(f32,64) -> bufB (q64) + qs
    k_quant<64, false><<<AGB, 256, 0, stream>>>((const float*)bufA, nullptr, (short*)bufB, qs, NNODES);
    // conv3 agg: bufB(q64) -> out (f32 + b3)
    k_agg3<64, 1><<<AGB, 256, 0, stream>>>((const short*)bufB, qs, rp2, col2, dinv2, b3, out, NNODES);
    // optional softmax (mode != 1)
    k_softmax<<<AGB, 256, 0, stream>>>(out, mode, NNODES);
}